// Round 1
// baseline (146.307 us; speedup 1.0000x reference)
//
#include <hip/hip_runtime.h>
#include <math.h>

// NeuralSplineCoupling: y[:, :3] = RQS(x[:, :3]; params = MLP([x[:,3:], c]))
//                       y[:, 3:] = x[:, 3:],  log_det = sum over 3 dims
// N = 500000, X_DIM=6, C_DIM=4, HID=128, KNOTS=16, SPLINE_DIM=47, OUT_DIM=141
//
// Round 13: r12 (LDS-staged weights) restructured from 4 waves -> 8 waves per
// 128-sample tile. Rationale: (1) phase-4 had 6 spline groups over 4 waves ->
// waves 0/1 ran TWO serial spline bodies while 2/3 idled; now 6 of 8 waves run
// exactly ONE body (critical path halved). (2) occupancy 2 -> 4 waves/SIMD
// (launch_bounds(512,4), 1-set MLP halves live acc state so regs fit 128).
// (3) staging is 10 rounds of 512 thr instead of 19 of 256. LDS unchanged
// (79360 B -> 2 blocks/CU).

#define TILE 128
#define NT   512
#define HID  128
#define OUTD 141
#define SRS  152     // halves per sample in shp16 (304 B rows)
#define BND  5.0f
#define T1   0.5413248546f   // ln(e-1): softplus(T1) = 1

typedef __bf16 bf16;
typedef _Float16 f16;
typedef __attribute__((ext_vector_type(8))) __bf16 bf16x8;
typedef __attribute__((ext_vector_type(8))) _Float16 f16x8;
typedef __attribute__((ext_vector_type(4))) _Float16 f16x4;
typedef __attribute__((ext_vector_type(2))) _Float16 f16x2;
typedef __attribute__((ext_vector_type(4))) float f32x4;

// fragment-index bases in the packed weight blob (fragment = 64 lanes x 16 B)
#define W3BASE 0         // 9 t3 x 4 kc = 36 tiles -> frags [0, 2304)
#define W1BASE 2304      // 8 tiles               -> frags [2304, 2816)
#define W2BASE 2816      // 8 m-tiles x 4 kc      -> frags [2816, 4864)
#define NFRAG  4864      // 77824 bytes total
#define B3P_OFF (NFRAG * 16)   // byte offset of b3p in d_ws

// LDS: wlds [0, 77824) = staged blob (same frag indexing as d_ws);
// shp16 [36864, 75776) overlays W1s+W2s (barrier-separated);
// shld [77824, 79360)
#define SMEM_BYTES 79360

// One thread per 8-elem A-fragment (W^T in A-layout: A[m=lane&15][k=lq*8+j]).
// k-permutation for W2/W3: feat = (kc*2+(j>>2))*16 + lq*4 + (j&3)  (f mapping,
// matches the in-lane D->B repack of the transposed chain — verified r11).
__global__ void nsc_prepack(const float* __restrict__ W1, const float* __restrict__ W2,
                            const float* __restrict__ W3, const float* __restrict__ b3,
                            bf16* __restrict__ Wall, float* __restrict__ b3p) {
    int f = blockIdx.x * 256 + threadIdx.x;
    int lane = f & 63, lm = lane & 15, lq = lane >> 4;
    if (f < W1BASE) {                                // W3^T frags
        int tk = f >> 6, t3 = tk >> 2, kc = tk & 3;
        int col = t3 * 16 + lm;
        bf16x8 pk;
        #pragma unroll
        for (int j = 0; j < 8; ++j) {
            int feat = ((kc * 2 + (j >> 2)) << 4) + (lq << 2) + (j & 3);
            pk[j] = (col < OUTD) ? (bf16)W3[feat * OUTD + col] : (bf16)0.f;
        }
        *(bf16x8*)&Wall[(size_t)f * 8] = pk;
    } else if (f < W2BASE) {                         // W1^T frags (identity k, 7 feats)
        int t = (f - W1BASE) >> 6;
        int m = t * 16 + lm;
        bf16x8 pk;
        #pragma unroll
        for (int j = 0; j < 8; ++j) {
            int k = lq * 8 + j;
            pk[j] = (k < 7) ? (bf16)W1[k * HID + m] : (bf16)0.f;
        }
        *(bf16x8*)&Wall[(size_t)f * 8] = pk;
    } else if (f < NFRAG) {                          // W2^T frags
        int tk = (f - W2BASE) >> 6, t2 = tk >> 2, kc = tk & 3;
        int m = t2 * 16 + lm;
        bf16x8 pk;
        #pragma unroll
        for (int j = 0; j < 8; ++j) {
            int feat = ((kc * 2 + (j >> 2)) << 4) + (lq << 2) + (j & 3);
            pk[j] = (bf16)W2[feat * HID + m];
        }
        *(bf16x8*)&Wall[(size_t)f * 8] = pk;
    } else if (f < NFRAG + 144) {                    // b3 padded to 144
        int i = f - NFRAG;
        b3p[i] = (i < OUTD) ? b3[i] : 0.f;
    }
}

__global__ __launch_bounds__(NT, 4) void nsc_main(
    const float* __restrict__ x, const float* __restrict__ c,
    const bf16* __restrict__ Wall, const float* __restrict__ b1,
    const float* __restrict__ b2, const float* __restrict__ b3p,
    float* __restrict__ out_y, float* __restrict__ out_ld, int N)
{
    __shared__ __align__(16) char smem[SMEM_BYTES];
    bf16*  wlds  = (bf16*)smem;                 // staged weight blob
    f16*   shp16 = (f16*)(smem + 36864);        // [128][SRS], overlays W1s+W2s
    float* shld  = (float*)(smem + 77824);      // [128][3]

    const int tid  = threadIdx.x;
    const int g0   = blockIdx.x * TILE;
    const int lane = tid & 63;
    const int wv   = tid >> 6;        // 0..7: wave owns samples wv*16 .. wv*16+15
    const int lm   = lane & 15;
    const int lq   = lane >> 4;
    const int sbase = wv * 16;

    // ---- Input loads first (overlap with staging) ----
    float vin[8];
    #pragma unroll
    for (int j = 0; j < 8; ++j) vin[j] = 0.f;
    {
        int g = g0 + sbase + lm;
        if (lq == 0 && g < N) {
            vin[0] = x[g * 6 + 3]; vin[1] = x[g * 6 + 4];
            vin[2] = x[g * 6 + 5];
            vin[3] = c[g * 4];     vin[4] = c[g * 4 + 1];
            vin[5] = c[g * 4 + 2]; vin[6] = c[g * 4 + 3];
        }
    }

    // ---- Stage the 77824 B weight blob: 10 x (dwordx4 load + b128 LDS store) ----
    {
        const float4* src = (const float4*)Wall;
        float4* dst = (float4*)smem;
        #pragma unroll
        for (int j = 0; j < 10; ++j) {
            int idx = tid + j * NT;           // 0..4863 (last round: tid<256)
            if (idx < NFRAG) dst[idx] = src[idx];
        }
    }
    __syncthreads();   // staging complete (drains vmcnt+lgkmcnt)

    // ---- Build B1 input fragment (B[k=lq*8+j][n=sample lm]) ----
    bf16x8 inb;
    {
        bf16x8 t;
        #pragma unroll
        for (int j = 0; j < 8; ++j) t[j] = (bf16)vin[j];
        inb = t;
    }

    // ---- Phase 1: h1^T = W1^T @ in^T + b1 ----
    f32x4 acc1[8];
    {
        #pragma unroll
        for (int t = 0; t < 8; ++t)
            acc1[t] = *(const f32x4*)&b1[t * 16 + lq * 4];
        #pragma unroll
        for (int t = 0; t < 8; ++t) {
            bf16x8 wf = *(const bf16x8*)&wlds[(size_t)((W1BASE + t * 64 + lane)) * 8];
            acc1[t] = __builtin_amdgcn_mfma_f32_16x16x32_bf16(wf, inb, acc1[t], 0, 0, 0);
        }
    }
    // in-lane D->B repack: B2 slot (kc,j) <- relu(D1[t = kc*2+(j>>2)].r[j&3])
    bf16x8 h1B[4];
    #pragma unroll
    for (int kc = 0; kc < 4; ++kc) {
        bf16x8 hb;
        #pragma unroll
        for (int j = 0; j < 8; ++j)
            hb[j] = (bf16)fmaxf(acc1[kc * 2 + (j >> 2)][j & 3], 0.f);
        h1B[kc] = hb;
    }

    // ---- Phase 2: h2^T = W2^T @ h1^T + b2 ----
    bf16x8 h2B[4];
    #pragma unroll
    for (int tp = 0; tp < 4; ++tp) {
        f32x4 acc[2];
        #pragma unroll
        for (int dt = 0; dt < 2; ++dt)
            acc[dt] = *(const f32x4*)&b2[(tp * 2 + dt) * 16 + lq * 4];
        #pragma unroll
        for (int kc = 0; kc < 4; ++kc)
            #pragma unroll
            for (int dt = 0; dt < 2; ++dt) {
                bf16x8 wf = *(const bf16x8*)&wlds[(size_t)((W2BASE + ((tp * 2 + dt) * 4 + kc) * 64 + lane)) * 8];
                acc[dt] = __builtin_amdgcn_mfma_f32_16x16x32_bf16(wf, h1B[kc], acc[dt], 0, 0, 0);
            }
        bf16x8 hb;
        #pragma unroll
        for (int j = 0; j < 8; ++j)
            hb[j] = (bf16)fmaxf(acc[j >> 2][j & 3], 0.f);
        h2B[tp] = hb;      // kc-group of next GEMM == tp (f mapping)
    }
    __syncthreads();   // BARRIER A: all waves done reading W1s/W2s -> shp16 free

    // ---- Phase 3: p^T = W3^T @ h2^T + b3 (W3s region: no alias) ----
    #pragma unroll
    for (int t3 = 0; t3 < 9; ++t3) {
        f32x4 acc = *(const f32x4*)&b3p[t3 * 16 + lq * 4];
        #pragma unroll
        for (int kc = 0; kc < 4; ++kc) {
            bf16x8 wf = *(const bf16x8*)&wlds[(size_t)((W3BASE + (t3 * 4 + kc) * 64 + lane)) * 8];
            acc = __builtin_amdgcn_mfma_f32_16x16x32_bf16(wf, h2B[kc], acc, 0, 0, 0);
        }
        {
            int s = sbase + lm;
            f16x4 pk = (f16x4){(f16)acc[0], (f16)acc[1],
                               (f16)acc[2], (f16)acc[3]};
            int off = t3 * 16 + lq * 4;   // off = col; 8B-aligned b64 store
            if (t3 < 8) {
                *(f16x4*)&shp16[s * SRS + off] = pk;
            } else {
                if (lq < 3) *(f16x4*)&shp16[s * SRS + off] = pk;
                else        shp16[s * SRS + 140] = pk[0];   // col 140 only
            }
        }
    }
    __syncthreads();   // BARRIER B: scatters visible to all waves

    // ---- Phase 4: spline; one 64-lane group per wave (waves 0..5), d uniform ----
    if (wv < 6) {
        const int grp = wv;
        const int d = grp >> 1;
        const int s = ((grp & 1) << 6) + lane;
        const int g = g0 + s;
        if (g < N) {
            const f16* pr = &shp16[s * SRS];
            float w_[16], h_[16], dl[15];
            if (d == 0) {               // p[0..46]
                f16x8 A0 = *(const f16x8*)&pr[0],  A1 = *(const f16x8*)&pr[8];
                f16x8 A2 = *(const f16x8*)&pr[16], A3 = *(const f16x8*)&pr[24];
                f16x8 A4 = *(const f16x8*)&pr[32], A5 = *(const f16x8*)&pr[40];
                #pragma unroll
                for (int i = 0; i < 8; ++i) {
                    w_[i] = (float)A0[i]; w_[8 + i] = (float)A1[i];
                    h_[i] = (float)A2[i]; h_[8 + i] = (float)A3[i];
                    dl[i] = (float)A4[i];
                }
                #pragma unroll
                for (int i = 0; i < 7; ++i) dl[8 + i] = (float)A5[i];
            } else if (d == 1) {        // p[47..93]
                float a47 = (float)pr[47];
                f16x8 A0 = *(const f16x8*)&pr[48], A1 = *(const f16x8*)&pr[56];
                f16x8 A2 = *(const f16x8*)&pr[64], A3 = *(const f16x8*)&pr[72];
                f16x8 A4 = *(const f16x8*)&pr[80], A5 = *(const f16x8*)&pr[88];
                w_[0] = a47;
                #pragma unroll
                for (int i = 0; i < 8; ++i) w_[1 + i] = (float)A0[i];
                #pragma unroll
                for (int i = 0; i < 7; ++i) w_[9 + i] = (float)A1[i];
                h_[0] = (float)A1[7];
                #pragma unroll
                for (int i = 0; i < 8; ++i) h_[1 + i] = (float)A2[i];
                #pragma unroll
                for (int i = 0; i < 7; ++i) h_[9 + i] = (float)A3[i];
                dl[0] = (float)A3[7];
                #pragma unroll
                for (int i = 0; i < 8; ++i) dl[1 + i] = (float)A4[i];
                #pragma unroll
                for (int i = 0; i < 6; ++i) dl[9 + i] = (float)A5[i];
            } else {                    // p[94..140]
                f16x2 B  = *(const f16x2*)&pr[94];
                f16x8 C0 = *(const f16x8*)&pr[96],  C1 = *(const f16x8*)&pr[104];
                f16x8 C2 = *(const f16x8*)&pr[112], C3 = *(const f16x8*)&pr[120];
                f16x8 C4 = *(const f16x8*)&pr[128], E  = *(const f16x8*)&pr[136];
                w_[0] = (float)B[0]; w_[1] = (float)B[1];
                #pragma unroll
                for (int i = 0; i < 8; ++i) w_[2 + i] = (float)C0[i];
                #pragma unroll
                for (int i = 0; i < 6; ++i) w_[10 + i] = (float)C1[i];
                h_[0] = (float)C1[6]; h_[1] = (float)C1[7];
                #pragma unroll
                for (int i = 0; i < 8; ++i) h_[2 + i] = (float)C2[i];
                #pragma unroll
                for (int i = 0; i < 6; ++i) h_[10 + i] = (float)C3[i];
                dl[0] = (float)C3[6]; dl[1] = (float)C3[7];
                #pragma unroll
                for (int i = 0; i < 8; ++i) dl[2 + i] = (float)C4[i];
                #pragma unroll
                for (int i = 0; i < 5; ++i) dl[10 + i] = (float)E[i];
            }

            // softmax without max-subtract: logits are O(1)
            float sw = 0.f, sh = 0.f;
            #pragma unroll
            for (int i = 0; i < 16; ++i) { w_[i] = __expf(w_[i]); sw += w_[i]; }
            #pragma unroll
            for (int i = 0; i < 16; ++i) { h_[i] = __expf(h_[i]); sh += h_[i]; }
            float cwn = 10.f * __builtin_amdgcn_rcpf(sw);
            float chn = 10.f * __builtin_amdgcn_rcpf(sh);
            #pragma unroll
            for (int i = 0; i < 16; ++i) { w_[i] *= cwn; h_[i] *= chn; }

            float xv = x[g * 6 + d];
            bool oob = (xv <= -BND) || (xv >= BND);
            float xm = oob ? -BND : xv;

            // bin scan; softplus deferred to the 2 selected derivs
            float cumx = -BND + w_[0], cumy = -BND + h_[0];
            float xk_b = -BND, yk_b = -BND;
            float wk = w_[0], hk = h_[0];
            float d0l = T1, d1l = dl[0];
            #pragma unroll
            for (int i = 1; i < 16; ++i) {
                bool ge = (xm >= cumx);
                if (ge) {
                    xk_b = cumx; yk_b = cumy;
                    wk = w_[i]; hk = h_[i];
                    d0l = dl[i - 1];
                    d1l = (i < 15) ? dl[i] : T1;
                }
                cumx += w_[i]; cumy += h_[i];
            }
            float d0 = (d0l > 15.f) ? d0l : __logf(1.f + __expf(d0l));
            float d1 = (d1l > 15.f) ? d1l : __logf(1.f + __expf(d1l));

            float rwk = __builtin_amdgcn_rcpf(wk);
            float sk = hk * rwk;
            float relx = (xm - xk_b) * rwk;
            relx = fminf(fmaxf(relx, 0.f), 1.f);
            float r1 = relx * (1.f - relx);
            float den = sk + (d1 + d0 - 2.f * sk) * r1;
            float iden = __builtin_amdgcn_rcpf(den);
            float num = hk * (sk * relx * relx + d0 * r1);
            float y = yk_b + num * iden;
            float omr = 1.f - relx;
            float arg = d1 * relx * relx + 2.f * sk * r1 + d0 * omr * omr;
            float ratio = sk * iden;
            float ld = __logf(ratio * ratio * arg);   // 2log(sk)+log(arg)-2log(den)
            if (oob) { y = xv; ld = 0.f; }

            out_y[g * 6 + d] = y;
            out_y[g * 6 + 3 + d] = x[g * 6 + 3 + d];  // upper pass-through (fp32)
            shld[s * 3 + d] = ld;
        }
    }
    __syncthreads();   // BARRIER C

    // ---- Phase 5: reduce log-det over the 3 dims ----
    if (tid < TILE) {
        int g = g0 + tid;
        if (g < N)
            out_ld[g] = shld[tid * 3] + shld[tid * 3 + 1] + shld[tid * 3 + 2];
    }
}

extern "C" void kernel_launch(void* const* d_in, const int* in_sizes, int n_in,
                              void* d_out, int out_size, void* d_ws, size_t ws_size,
                              hipStream_t stream) {
    const float* x  = (const float*)d_in[0];
    const float* c  = (const float*)d_in[1];
    const float* W1 = (const float*)d_in[2];
    const float* b1 = (const float*)d_in[3];
    const float* W2 = (const float*)d_in[4];
    const float* b2 = (const float*)d_in[5];
    const float* W3 = (const float*)d_in[6];
    const float* b3 = (const float*)d_in[7];

    const int N = in_sizes[0] / 6;              // 500000
    float* out_y  = (float*)d_out;
    float* out_ld = (float*)d_out + (size_t)N * 6;

    bf16*  Wall = (bf16*)d_ws;                          // 77824 B blob
    float* b3p  = (float*)((char*)d_ws + B3P_OFF);      // 576 B

    int nthreads = NFRAG + 144;                 // 5008
    nsc_prepack<<<(nthreads + 255) / 256, 256, 0, stream>>>(W1, W2, W3, b3,
                                                            Wall, b3p);

    int nblocks = (N + TILE - 1) / TILE;        // 3907
    nsc_main<<<nblocks, NT, 0, stream>>>(x, c, Wall, b1, b2, b3p,
                                         out_y, out_ld, N);
}